// Round 1
// 324.692 us; speedup vs baseline: 1.0907x; 1.0907x over previous
//
#include <hip/hip_runtime.h>
#include <math.h>

#define SEQ 2048
#define NBATCH 2
#define NHEAD 16
#define HDIM 64
#define DMODEL 1024
#define DFF 4096

typedef __attribute__((ext_vector_type(8))) __bf16 bf16x8;
typedef __attribute__((ext_vector_type(4))) float f32x4;

// native bf16 convert (gfx950, RNE)
__device__ __forceinline__ unsigned short f2bf(float f) {
    union { __bf16 b; unsigned short u; } c;
    c.b = (__bf16)f;
    return c.u;
}
__device__ __forceinline__ float bf2f(unsigned short u) {
    union { unsigned int u; float f; } c;
    c.u = ((unsigned int)u) << 16;
    return c.f;
}

// async global->LDS, 16 B per lane; LDS dest = wave-uniform base + lane*16
__device__ __forceinline__ void async16(const unsigned short* g, unsigned short* l) {
    __builtin_amdgcn_global_load_lds(
        (const __attribute__((address_space(1))) unsigned int*)(g),
        (__attribute__((address_space(3))) unsigned int*)(l),
        16, 0, 0);
}

// ---------------------------------------------------------------------------
// Fused prep: 6 weight transposes (fp32 [K][N] -> bf16 [N][K]) + x->bf16 +
// qkv bias concat, one launch. Tile = 64x64.
// ---------------------------------------------------------------------------
__device__ __forceinline__ void transpose_tile(
    const float* __restrict__ in, unsigned short* __restrict__ out,
    int K, int N, int k0, int n0, int t, unsigned short* sT)
{
    {
        const int r = t >> 4, c4 = t & 15;
#pragma unroll
        for (int i = 0; i < 4; i++) {
            const int k = r + (i << 4);
            const float4 v = *(const float4*)(in + (size_t)(k0 + k) * N + n0 + (c4 << 2));
            sT[((c4 << 2) + 0) * 72 + k] = f2bf(v.x);
            sT[((c4 << 2) + 1) * 72 + k] = f2bf(v.y);
            sT[((c4 << 2) + 2) * 72 + k] = f2bf(v.z);
            sT[((c4 << 2) + 3) * 72 + k] = f2bf(v.w);
        }
    }
    __syncthreads();
    {
        const int n = t >> 2, cc = t & 3;
#pragma unroll
        for (int i = 0; i < 2; i++) {
            const int c = cc + (i << 2);
            *(uint4*)(out + (size_t)(n0 + n) * K + k0 + (c << 3)) =
                *(const uint4*)(&sT[n * 72 + (c << 3)]);
        }
    }
}

__global__ __launch_bounds__(256) void prep_kernel(
    const float* __restrict__ x,
    const float* __restrict__ Wq, const float* __restrict__ Wk,
    const float* __restrict__ Wv, const float* __restrict__ Wo,
    const float* __restrict__ W1, const float* __restrict__ W2,
    const float* __restrict__ bq, const float* __restrict__ bk,
    const float* __restrict__ bv,
    unsigned short* __restrict__ xb, unsigned short* __restrict__ WqkvT,
    unsigned short* __restrict__ WoT, unsigned short* __restrict__ W1T,
    unsigned short* __restrict__ W2T, float* __restrict__ bqkv)
{
    __shared__ unsigned short sT[64 * 72];
    const int bid = blockIdx.x, t = threadIdx.x;
    if (bid < 1024) {
        const int wsel = bid >> 8, tt = bid & 255;
        const float* in = (wsel == 0) ? Wq : (wsel == 1) ? Wk : (wsel == 2) ? Wv : Wo;
        unsigned short* outp = (wsel == 3) ? WoT : WqkvT + (size_t)wsel * 1024 * 1024;
        transpose_tile(in, outp, 1024, 1024, (tt >> 4) << 6, (tt & 15) << 6, t, sT);
    } else if (bid < 2048) {
        const int tt = bid - 1024;
        transpose_tile(W1, W1T, 1024, 4096, (tt >> 6) << 6, (tt & 63) << 6, t, sT);
    } else if (bid < 3072) {
        const int tt = bid - 2048;
        transpose_tile(W2, W2T, 4096, 1024, (tt >> 4) << 6, (tt & 15) << 6, t, sT);
    } else if (bid < 7168) {
        const size_t i = ((size_t)(bid - 3072) * 256 + t) << 2;
        const float4 v = *(const float4*)(x + i);
        ushort4 b;
        b.x = f2bf(v.x); b.y = f2bf(v.y); b.z = f2bf(v.z); b.w = f2bf(v.w);
        *(ushort4*)(xb + i) = b;
    } else {
        const int i = (bid - 7168) * 256 + t;
        float v;
        if (i < 1024)       v = bq[i];
        else if (i < 2048)  v = bk[i - 1024];
        else                v = bv[i - 2048];
        bqkv[i] = v;
    }
}

// ---------------------------------------------------------------------------
// m97-style bf16 MFMA GEMM + XOR-swizzled LDS (0 bank conflicts, verified).
// 128x128 tile, BK=64. XCD swizzle for L2. Split-K via gridDim.z.
// EPI: 0 = +bias, QKV scatter; Q is PRE-SCALED by log2(e) so attention can
//          use a bare v_exp. (Q,K bf16 [bh][s][d]; V bf16 [bh][d][s])
//      2 = fast-gelu(+bias) -> bf16    3 = raw fp32 partial (split-K)
// ---------------------------------------------------------------------------
template<int EPI>
__global__ __launch_bounds__(256) void gemm_bf16_kernel(
    const unsigned short* __restrict__ A, const unsigned short* __restrict__ Bt,
    const float* __restrict__ bias, float* __restrict__ outF,
    unsigned short* __restrict__ outB, unsigned short* __restrict__ outQ,
    unsigned short* __restrict__ outK, unsigned short* __restrict__ outV,
    int N, int K, size_t pstride)
{
    __shared__ unsigned short sA[128 * 64];
    __shared__ unsigned short sB[128 * 64];
    const int gx = gridDim.x, gy = gridDim.y;
    const int flat = blockIdx.y * gx + blockIdx.x;
    const int xcd = flat & 7, slot = flat >> 3;
    const int rx = gx >> 1, ry = gy >> 2;
    const int bx = (xcd & 1) * rx + (slot % rx);
    const int by = (xcd >> 1) * ry + (slot / rx);
    const int m0 = by << 7;
    const int n0 = bx << 7;
    const int kspan = K / gridDim.z;
    const int kbeg = blockIdx.z * kspan;

    const int t = threadIdx.x;
    const int w = t >> 6, l = t & 63, li = l & 15, quad = l >> 4;
    const int wm = (w >> 1) << 6, wn = (w & 1) << 6;
    const int srow = l >> 3;
    const int scol = ((l & 7) ^ srow) << 3;        // swizzled global chunk

    f32x4 acc[4][4];
#pragma unroll
    for (int mi = 0; mi < 4; mi++)
#pragma unroll
        for (int ni = 0; ni < 4; ni++)
            acc[mi][ni] = (f32x4){0.f, 0.f, 0.f, 0.f};

    for (int k0 = kbeg; k0 < kbeg + kspan; k0 += 64) {
#pragma unroll
        for (int i = 0; i < 4; i++) {
            const int c = (w << 2) + i;            // chunk: 8 rows = 1 KB
            async16(A  + (size_t)(m0 + (c << 3) + srow) * K + k0 + scol, &sA[c << 9]);
            async16(Bt + (size_t)(n0 + (c << 3) + srow) * K + k0 + scol, &sB[c << 9]);
        }
        __syncthreads();
#pragma unroll
        for (int ks = 0; ks < 2; ks++) {
            bf16x8 af[4], bfr[4];
#pragma unroll
            for (int mi = 0; mi < 4; mi++)
                af[mi] = *(const bf16x8*)(&sA[((wm + (mi << 4) + li) << 6) +
                                             ((((ks << 2) + quad) ^ (li & 7)) << 3)]);
#pragma unroll
            for (int ni = 0; ni < 4; ni++)
                bfr[ni] = *(const bf16x8*)(&sB[((wn + (ni << 4) + li) << 6) +
                                              ((((ks << 2) + quad) ^ (li & 7)) << 3)]);
#pragma unroll
            for (int mi = 0; mi < 4; mi++)
#pragma unroll
                for (int ni = 0; ni < 4; ni++)
                    acc[mi][ni] = __builtin_amdgcn_mfma_f32_16x16x32_bf16(
                        af[mi], bfr[ni], acc[mi][ni], 0, 0, 0);
        }
        __syncthreads();
    }

    if (EPI == 0) {
        const int region = n0 >> 10;
        const int bq_ = m0 >> 11;
        const int sloc = (m0 & 2047) + wm + (quad << 2);
        const float qscale = (region == 0) ? 1.4426950408889634f : 1.0f;
#pragma unroll
        for (int ni = 0; ni < 4; ni++) {
            const int col = n0 + wn + (ni << 4) + li;
            const int c = col & 1023;
            const int h = c >> 6, d = c & 63;
            const float bcol = bias[col];
            if (region < 2) {
                unsigned short* base = ((region == 0) ? outQ : outK) +
                    (((size_t)(bq_ * NHEAD + h)) << 17) + d;
#pragma unroll
                for (int mi = 0; mi < 4; mi++)
#pragma unroll
                    for (int r = 0; r < 4; r++)
                        base[(size_t)(sloc + (mi << 4) + r) << 6] =
                            f2bf((acc[mi][ni][r] + bcol) * qscale);
            } else {
                unsigned short* base = outV + (((size_t)(bq_ * NHEAD + h)) << 17) +
                    ((size_t)d << 11) + sloc;
#pragma unroll
                for (int mi = 0; mi < 4; mi++) {
                    ushort4 pk;
                    pk.x = f2bf(acc[mi][ni][0] + bcol);
                    pk.y = f2bf(acc[mi][ni][1] + bcol);
                    pk.z = f2bf(acc[mi][ni][2] + bcol);
                    pk.w = f2bf(acc[mi][ni][3] + bcol);
                    *(ushort4*)(base + (mi << 4)) = pk;
                }
            }
        }
    } else {
        float* outFz = outF + (size_t)blockIdx.z * pstride;
#pragma unroll
        for (int mi = 0; mi < 4; mi++) {
#pragma unroll
            for (int ni = 0; ni < 4; ni++) {
#pragma unroll
                for (int r = 0; r < 4; r++) {
                    const int row = m0 + wm + (mi << 4) + (quad << 2) + r;
                    const int col = n0 + wn + (ni << 4) + li;
                    float v = acc[mi][ni][r];
                    if (EPI == 2) {
                        v += bias[col];
                        // gelu ~ v / (1 + 2^(c1*v + c3*v^3)), raw v_exp + rcp
                        const float u = v * v;
                        const float wq = fmaf(-0.1029432f, u, -2.30220786f);
                        const float e = __builtin_amdgcn_exp2f(v * wq);
                        const float ge = v * __builtin_amdgcn_rcpf(1.0f + e);
                        outB[(size_t)row * N + col] = f2bf(ge);
                    } else {
                        outFz[(size_t)row * N + col] = v;
                    }
                }
            }
        }
    }
}

// ---------------------------------------------------------------------------
// Flash attention, S-transposed, 32 q/wave, KEY-SPLIT x2 inside the block:
// 512 threads, waves 0-3 stream keys 0..1023, waves 4-7 keys 1024..2047 over
// the same 128 q-rows. Doubles resident waves (8 -> 16 per CU; kernel was
// latency-bound at Occupancy 19%, MfmaUtil 26%, VALU 33%). Partials
// (unnormalized O + rowsums) combined through the dead staging LDS at the
// end -- no extra kernel, same HBM traffic (each group reads its key half).
// LDS = 2 groups x dbuf K/V (64 KB) + per-wave 32-key P (16 KB) = 80 KB
// -> exactly 2 blocks/CU. P processed in 32-key chunks so half-1's exp
// (VALU) overlaps half-0's PV (MFMA); setprio(1) around the PV cluster.
// sP swizzle for 64 B rows: chunk ^= (li>>1)&3 (2-way = free on both the
// ds_write_b64 and ds_read_b128 sides; write/read address maps verified).
// Softmax: Q pre-scaled by log2e, bare v_exp. Row-sums via ones-MFMA.
// ---------------------------------------------------------------------------
__global__ __launch_bounds__(512, 4) void attn_kernel(
    const unsigned short* __restrict__ Qb, const unsigned short* __restrict__ Kb,
    const unsigned short* __restrict__ Vt, unsigned short* __restrict__ AOb)
{
    __shared__ __align__(16) unsigned short sK[2][2][64 * 64];
    __shared__ __align__(16) unsigned short sV[2][2][64 * 64];
    __shared__ __align__(16) unsigned short sP[8][32 * 32];
    const int t = threadIdx.x, w = t >> 6, l = t & 63;
    const int li = l & 15, quad = l >> 4;
    const int g = w >> 2, wg = w & 3;               // key-half group, wave-in-group
    const int p = blockIdx.x;                       // 512 blocks
    const int xcd = p & 7, slot = p >> 3;           // slot 0..63
    const int bh = (xcd << 2) + (slot >> 4);        // 4 heads per XCD
    const int q0 = (slot & 15) << 7;                // 128-row q tile
    const unsigned short* Qh = Qb + ((size_t)bh << 17);
    const unsigned short* Kh = Kb + ((size_t)bh << 17);
    const unsigned short* Vh = Vt + ((size_t)bh << 17);
    const int qw = q0 + (wg << 5);                  // wave's 32 q-rows
    const int ssw = ((l & 7) ^ (l >> 3)) << 3;      // swizzled staging chunk
    const int lq7 = li & 7;
    const int sws = (li >> 1) & 3;                  // sP chunk swizzle (64 B rows)
    const int kb = g << 10;                         // group's key base

    // Q as B-frag of S^T (per m-tile): lane holds Q[qw+16m+li][32h+8quad..+7]
    bf16x8 bq[2][2];
#pragma unroll
    for (int m = 0; m < 2; m++)
#pragma unroll
        for (int h = 0; h < 2; h++)
            bq[m][h] = *(const bf16x8*)(Qh + ((size_t)(qw + (m << 4) + li) << 6) +
                                        (h << 5) + (quad << 3));

    bf16x8 bone;
#pragma unroll
    for (int j = 0; j < 8; j++) bone[j] = (__bf16)1.0f;

    f32x4 o[2][4];
    f32x4 accl[2];
#pragma unroll
    for (int m = 0; m < 2; m++) {
        accl[m] = (f32x4){0.f, 0.f, 0.f, 0.f};
#pragma unroll
        for (int d = 0; d < 4; d++) o[m][d] = (f32x4){0.f, 0.f, 0.f, 0.f};
    }
    const f32x4 z = (f32x4){0.f, 0.f, 0.f, 0.f};
    unsigned short* myP = &sP[w][0];

    // loop-invariant P-write addresses: row = 16m+li (q), 32-key rows of 64 B;
    // logical 8-key chunk (nt2*2 + quad>>1) XOR sws, +8 B for odd quads
    unsigned short* wp[2][2];
#pragma unroll
    for (int m = 0; m < 2; m++)
#pragma unroll
        for (int nt2 = 0; nt2 < 2; nt2++)
            wp[m][nt2] = myP + (((m << 4) + li) << 5) +
                         ((((nt2 << 1) + (quad >> 1)) ^ sws) << 3) + ((quad & 1) << 2);

#define STAGE(buf, kc)                                                              \
    {                                                                               \
        _Pragma("unroll")                                                           \
        for (int i = 0; i < 4; i++) {                                               \
            const int cc = (wg << 2) + i;                                           \
            if (cc < 8)                                                             \
                async16(Kh + ((size_t)(kb + (kc) + (cc << 3) + (l >> 3)) << 6) + ssw, \
                        &sK[g][buf][cc << 9]);                                      \
            else                                                                    \
                async16(Vh + ((size_t)(((cc - 8) << 3) + (l >> 3)) << 11) + kb + (kc) + ssw, \
                        &sV[g][buf][(cc - 8) << 9]);                                \
        }                                                                           \
    }

    STAGE(0, 0);
    __syncthreads();

    for (int it = 0; it < 16; it++) {
        const int cur = it & 1;
        if (it + 1 < 16) STAGE(cur ^ 1, (it + 1) << 6);

#pragma unroll
        for (int half = 0; half < 2; half++) {
            // S^T for this 32-key half: 2 x 16-key tiles, exp, write P
#pragma unroll
            for (int nt2 = 0; nt2 < 2; nt2++) {
                const int nt = (half << 1) + nt2;
                const bf16x8 ak0 = *(const bf16x8*)(&sK[g][cur][(((nt << 4) + li) << 6) +
                                                                 ((quad ^ lq7) << 3)]);
                const bf16x8 ak1 = *(const bf16x8*)(&sK[g][cur][(((nt << 4) + li) << 6) +
                                                                 (((4 + quad) ^ lq7) << 3)]);
#pragma unroll
                for (int m = 0; m < 2; m++) {
                    f32x4 sc = __builtin_amdgcn_mfma_f32_16x16x32_bf16(ak0, bq[m][0], z, 0, 0, 0);
                    sc = __builtin_amdgcn_mfma_f32_16x16x32_bf16(ak1, bq[m][1], sc, 0, 0, 0);
                    ushort4 pk;
                    pk.x = f2bf(__builtin_amdgcn_exp2f(sc[0]));
                    pk.y = f2bf(__builtin_amdgcn_exp2f(sc[1]));
                    pk.z = f2bf(__builtin_amdgcn_exp2f(sc[2]));
                    pk.w = f2bf(__builtin_amdgcn_exp2f(sc[3]));
                    *(ushort4*)wp[m][nt2] = pk;
                }
            }

            // A-frags of P (wave-private LDS, DS in-order, no barrier needed)
            bf16x8 ap[2];
#pragma unroll
            for (int m = 0; m < 2; m++)
                ap[m] = *(const bf16x8*)(myP + (((m << 4) + li) << 5) +
                                         ((quad ^ sws) << 3));

            __builtin_amdgcn_s_setprio(1);
#pragma unroll
            for (int m = 0; m < 2; m++)
                accl[m] = __builtin_amdgcn_mfma_f32_16x16x32_bf16(ap[m], bone, accl[m], 0, 0, 0);
            // PV for this half: V-frag reads shared across m
#pragma unroll
            for (int dt = 0; dt < 4; dt++) {
                const bf16x8 bv = *(const bf16x8*)(&sV[g][cur][(((dt << 4) + li) << 6) +
                                                                ((((half << 2) + quad) ^ lq7) << 3)]);
#pragma unroll
                for (int m = 0; m < 2; m++)
                    o[m][dt] = __builtin_amdgcn_mfma_f32_16x16x32_bf16(ap[m], bv, o[m][dt], 0, 0, 0);
            }
            __builtin_amdgcn_s_setprio(0);
        }
        __syncthreads();
    }

    // ---- cross-group combine through the (now dead) staging LDS ----
    f32x4* oex = (f32x4*)&sK[0][0][0];   // 4wg x 2m x 4dt x 64 lanes x 16B = 32 KB
    f32x4* lex = (f32x4*)&sV[0][0][0];   // 4wg x 2m x 64 lanes x 16B = 8 KB
    if (g == 1) {
#pragma unroll
        for (int m = 0; m < 2; m++) {
            lex[(((wg << 1) + m) << 6) + l] = accl[m];
#pragma unroll
            for (int dt = 0; dt < 4; dt++)
                oex[(((((wg << 1) + m) << 2) + dt) << 6) + l] = o[m][dt];
        }
    }
    __syncthreads();
    if (g == 0) {
        const int b = bh >> 4, h = bh & 15;
#pragma unroll
        for (int m = 0; m < 2; m++) {
            const f32x4 la = lex[(((wg << 1) + m) << 6) + l];
            float inv[4];
#pragma unroll
            for (int r = 0; r < 4; r++)
                inv[r] = __builtin_amdgcn_rcpf(accl[m][r] + la[r]);
#pragma unroll
            for (int dt = 0; dt < 4; dt++) {
                const f32x4 oa = oex[(((((wg << 1) + m) << 2) + dt) << 6) + l];
#pragma unroll
                for (int r = 0; r < 4; r++) {
                    const int row = qw + (m << 4) + (quad << 2) + r;
                    const int col = (h << 6) + (dt << 4) + li;
                    AOb[((size_t)b * SEQ + row) * DMODEL + col] =
                        f2bf((o[m][dt][r] + oa[r]) * inv[r]);
                }
            }
        }
    }
#undef STAGE
}

// ---------------------------------------------------------------------------
// Fused split-K reduce + bias + residual + LayerNorm. RESB: residual dtype
// (0 = fp32 residF, 1 = bf16 residB). Outputs optional (outF fp32 / outB bf16).
// ---------------------------------------------------------------------------
template<int RESB>
__global__ __launch_bounds__(256) void ln_fuse_kernel(
    const float* __restrict__ P0, const float* __restrict__ P1,
    const float* __restrict__ residF, const unsigned short* __restrict__ residB,
    const float* __restrict__ bias,
    const float* __restrict__ g, const float* __restrict__ be,
    float* __restrict__ outF, unsigned short* __restrict__ outB)
{
    __shared__ float red[8];
    const int row = blockIdx.x, t = threadIdx.x;
    const size_t base = (size_t)row * DMODEL + (t << 2);
    const float4 a = *(const float4*)(P0 + base);
    const float4 b = *(const float4*)(P1 + base);
    float4 c;
    if (RESB) {
        const ushort4 cb = *(const ushort4*)(residB + base);
        c.x = bf2f(cb.x); c.y = bf2f(cb.y); c.z = bf2f(cb.z); c.w = bf2f(cb.w);
    } else {
        c = *(const float4*)(residF + base);
    }
    const float4 bi = *(const float4*)(bias + (t << 2));
    float4 v;
    v.x = a.x + b.x + c.x + bi.x;
    v.y = a.y + b.y + c.y + bi.y;
    v.z = a.z + b.z + c.z + bi.z;
    v.w = a.w + b.w + c.w + bi.w;
    float s = v.x + v.y + v.z + v.w;
    float s2 = v.x * v.x + v.y * v.y + v.z * v.z + v.w * v.w;
#pragma unroll
    for (int m = 1; m < 64; m <<= 1) {
        s += __shfl_xor(s, m, 64);
        s2 += __shfl_xor(s2, m, 64);
    }
    if ((t & 63) == 0) { red[t >> 6] = s; red[4 + (t >> 6)] = s2; }
    __syncthreads();
    s = red[0] + red[1] + red[2] + red[3];
    s2 = red[4] + red[5] + red[6] + red[7];
    const float mu = s * (1.0f / 1024.0f);
    const float var = s2 * (1.0f / 1024.0f) - mu * mu;
    const float rs = rsqrtf(var + 1e-5f);
    const float4 gg = *(const float4*)(g + (t << 2));
    const float4 bb = *(const float4*)(be + (t << 2));
    float4 ov;
    ov.x = (v.x - mu) * rs * gg.x + bb.x;
    ov.y = (v.y - mu) * rs * gg.y + bb.y;
    ov.z = (v.z - mu) * rs * gg.z + bb.z;
    ov.w = (v.w - mu) * rs * gg.w + bb.w;
    if (outF) *(float4*)(outF + base) = ov;
    if (outB) {
        ushort4 ob;
        ob.x = f2bf(ov.x); ob.y = f2bf(ov.y); ob.z = f2bf(ov.z); ob.w = f2bf(ov.w);
        *(ushort4*)(outB + base) = ob;
    }
}

// ---------------------------------------------------------------------------
extern "C" void kernel_launch(void* const* d_in, const int* in_sizes, int n_in,
                              void* d_out, int out_size, void* d_ws, size_t ws_size,
                              hipStream_t stream)
{
    (void)in_sizes; (void)n_in; (void)out_size; (void)ws_size;
    const float* x   = (const float*)d_in[0];
    const float* Wq  = (const float*)d_in[1];
    const float* bq  = (const float*)d_in[2];
    const float* Wk  = (const float*)d_in[3];
    const float* bk  = (const float*)d_in[4];
    const float* Wv  = (const float*)d_in[5];
    const float* bv  = (const float*)d_in[6];
    const float* Wo  = (const float*)d_in[7];
    const float* bo  = (const float*)d_in[8];
    const float* W1  = (const float*)d_in[9];
    const float* b1  = (const float*)d_in[10];
    const float* W2  = (const float*)d_in[11];
    const float* b2  = (const float*)d_in[12];
    const float* g1  = (const float*)d_in[13];
    const float* be1 = (const float*)d_in[14];
    const float* g2  = (const float*)d_in[15];
    const float* be2 = (const float*)d_in[16];
    float* out = (float*)d_out;

    char* ws = (char*)d_ws;
    unsigned short* WqkvT = (unsigned short*)(ws + 0);          // 3072x1024 bf16
    unsigned short* WoT   = (unsigned short*)(ws + 6291456);    // 1024x1024 bf16
    unsigned short* W1T   = (unsigned short*)(ws + 8388608);    // 4096x1024 bf16
    unsigned short* W2T   = (unsigned short*)(ws + 16777216);   // 1024x4096 bf16
    float* bqkv           = (float*)(ws + 25165824);            // 3072 f32
    unsigned short* xb    = (unsigned short*)(ws + 25178112);   // x bf16, 8 MB
    unsigned short* Qb    = (unsigned short*)(ws + 33566720);   // [32][2048][64]
    unsigned short* Kb    = (unsigned short*)(ws + 41955328);   // [32][2048][64]
    unsigned short* Vt    = (unsigned short*)(ws + 50343936);   // [32][64][2048]
    unsigned short* AOb   = (unsigned short*)(ws + 58732544);   // [4096][1024] bf16
    unsigned short* x1b   = (unsigned short*)(ws + 83898368);   // [4096][1024] bf16 (post-LN1)
    unsigned short* hb    = (unsigned short*)(ws + 92286976);   // [4096][4096] bf16 (32 MB)
    // overlays (sequentially dead regions):
    float* Po0 = (float*)(ws + 92286976);            // O-proj partial z=0 (pre-FF1, over hb)
    float* Po1 = (float*)(ws + 92286976 + 16777216); // O-proj partial z=1
    float* Pf0 = (float*)(ws + 33566720);            // FF2 partial z=0 (over Qb/Kb)
    float* Pf1 = (float*)(ws + 50343936);            // FF2 partial z=1 (over Vt/AOb)

    // ---- prep (single launch) ----
    prep_kernel<<<7180, 256, 0, stream>>>(
        x, Wq, Wk, Wv, Wo, W1, W2, bq, bk, bv,
        xb, WqkvT, WoT, W1T, W2T, bqkv);

    // ---- QKV projection (fused, N=3072; Q pre-scaled by log2e) ----
    gemm_bf16_kernel<0><<<dim3(24, 32), 256, 0, stream>>>(
        xb, WqkvT, bqkv, nullptr, nullptr, Qb, Kb, Vt, 3072, 1024, 0);

    // ---- attention -> AOb (bf16); key-split x2 inside 512-thread blocks ----
    attn_kernel<<<512, 512, 0, stream>>>(Qb, Kb, Vt, AOb);

    // ---- output projection, split-K=2 -> partials ----
    gemm_bf16_kernel<3><<<dim3(8, 32, 2), 256, 0, stream>>>(
        AOb, WoT, nullptr, Po0, nullptr, nullptr, nullptr, nullptr, 1024, 1024,
        (size_t)4096 * 1024);

    // ---- LN1 = LN(Po0+Po1+x+bo) -> x1b bf16 only ----
    ln_fuse_kernel<0><<<4096, 256, 0, stream>>>(
        Po0, Po1, x, nullptr, bo, g1, be1, nullptr, x1b);

    // ---- FF1 + fast GELU -> hb bf16 ----
    gemm_bf16_kernel<2><<<dim3(32, 32), 256, 0, stream>>>(
        x1b, W1T, b1, nullptr, hb, nullptr, nullptr, nullptr, 4096, 1024, 0);

    // ---- FF2, split-K=2 -> partials ----
    gemm_bf16_kernel<3><<<dim3(8, 32, 2), 256, 0, stream>>>(
        hb, W2T, nullptr, Pf0, nullptr, nullptr, nullptr, nullptr, 1024, 4096,
        (size_t)4096 * 1024);

    // ---- LN2 = LN(Pf0+Pf1+x1b+b2) -> d_out ----
    ln_fuse_kernel<1><<<4096, 256, 0, stream>>>(
        Pf0, Pf1, nullptr, x1b, b2, g2, be2, out, nullptr);
}